// Round 2
// baseline (207.159 us; speedup 1.0000x reference)
//
#include <hip/hip_runtime.h>

// Fused: per-channel affine+relu -> dilated(2) 3x3 box-sum (zero pad) ->
// sigmoid gate -> multiply -> 2x nearest upsample -> add y.
//
// Mapping: 1 thread = 2 adjacent input pixels (w0, w0+1) -> 4x2 output block.
// Lanes stride 16 B on y/out so every float4 load/store instruction is fully
// contiguous across the wave (R4 post-mortem: 8-pixel strips made each
// y/out dwordx4 instruction touch 64 cache lines instead of 16 -> VMEM
// request-bound at 2.5 TB/s).
// x taps: 3 float2 loads per row (w0-2..w0+3), UNCONDITIONAL with clamped
// addresses (no exec-mask branches; R3 post-mortem), masked arithmetically
// post-relu. Plain cached stores (nt caused 2.5x write amplification).
//
// R5: XCD-chunked block swizzle (kept: -24 MB HBM fetch, matters once
// BW-bound). 12288 % 8 == 0 -> bijective.
//
// R6: VGPR_Count was 16 -- the register allocator SERIALIZED the 11
// up-front loads (26+ dest VGPRs needed) into load/waitcnt/consume chunks,
// exposing ~10 sequential memory latencies per wave (~15K cy wave lifetime,
// which is exactly why no pipe showed >40% utilization). The asm memory
// clobber after the load block pins all loads before any consumption ->
// all destinations stay live -> single exposed latency per wave.

#define DIA 2

__global__ __launch_bounds__(256) void fused_kernel(
    const float* __restrict__ x, const float* __restrict__ y,
    const float* __restrict__ w1v, const float* __restrict__ b1v,
    const float* __restrict__ w2v, const float* __restrict__ b2v,
    float* __restrict__ out)
{
    constexpr int C = 3, H = 512, W = 512, W2 = 1024;
    constexpr int NBLK = 12288, CHUNK = NBLK / 8;

    // XCD-aware swizzle: hardware assigns consecutive blockIdx round-robin
    // across 8 XCDs; remap so each XCD owns a contiguous logical chunk.
    int g = blockIdx.x;
    int l = (g & 7) * CHUNK + (g >> 3);

    int idx = l * 256 + threadIdx.x;
    int wp = idx & (W / 2 - 1);                              // 0..255, lane-contiguous
    int h  = __builtin_amdgcn_readfirstlane((idx >> 8) & (H - 1));
    int bc = __builtin_amdgcn_readfirstlane(idx >> 17);      // 0..23 (b*C + c)
    int c  = bc % C;
    int w0 = wp * 2;                                         // even, 0..510

    const float s_w1 = w1v[c], s_b1 = b1v[c];
    const float s_w2 = w2v[c], s_b2 = b2v[c];

    const float* __restrict__ xrow = x + ((size_t)bc * H + (size_t)h) * W;

    const bool ok0 = (h >= DIA), ok2 = (h < H - DIA);
    const bool lok = (w0 > 0), rok = (w0 + 2 < W);
    const float m0 = ok0 ? 1.f : 0.f;
    const float m2 = ok2 ? 1.f : 0.f;
    const float mL = lok ? 1.f : 0.f;
    const float mR = rok ? 1.f : 0.f;

    // Clamped, always-in-bounds addresses (8B-aligned: offsets all even).
    const float* r1 = xrow;
    const float* r0 = ok0 ? (xrow - DIA * W) : xrow;
    const float* r2 = ok2 ? (xrow + DIA * W) : xrow;
    const int wl = lok ? (w0 - 2) : w0;
    const int wr = rok ? (w0 + 2) : w0;

    // ---- issue ALL global loads up front, unconditionally ----
    float2 L0 = *(const float2*)(r0 + wl);
    float2 M0 = *(const float2*)(r0 + w0);
    float2 R0 = *(const float2*)(r0 + wr);
    float2 L1 = *(const float2*)(r1 + wl);
    float2 M1 = *(const float2*)(r1 + w0);
    float2 R1 = *(const float2*)(r1 + wr);
    float2 L2 = *(const float2*)(r2 + wl);
    float2 M2 = *(const float2*)(r2 + w0);
    float2 R2 = *(const float2*)(r2 + wr);

    size_t obase = (((size_t)bc * (2 * H) + (size_t)(2 * h)) * W2) + (size_t)(2 * w0);
    float4 ya = *(const float4*)(y + obase);
    float4 yb = *(const float4*)(y + obase + W2);

    // R6: pin every load above this point with all destinations live.
    // Without this, the allocator reuses 16 VGPRs and serializes the
    // memory pipeline into ~10 exposed latencies per wave.
    asm volatile("" ::: "memory");

    // ---- compute ----
    auto act = [&](float v) { return fmaxf(fmaf(v, s_w1, s_b1), 0.f); };

    // center (= x_r): always valid
    float xo0 = act(M1.x);
    float xo1 = act(M1.y);

    float sum0 = mL * act(L1.x) + xo0 + mR * act(R1.x);
    float sum1 = mL * act(L1.y) + xo1 + mR * act(R1.y);
    sum0 += m0 * (mL * act(L0.x) + act(M0.x) + mR * act(R0.x));
    sum1 += m0 * (mL * act(L0.y) + act(M0.y) + mR * act(R0.y));
    sum0 += m2 * (mL * act(L2.x) + act(M2.x) + mR * act(R2.x));
    sum1 += m2 * (mL * act(L2.y) + act(M2.y) + mR * act(R2.y));

    float z0 = fmaf(sum0, s_w2, s_b2);
    float z1 = fmaf(sum1, s_w2, s_b2);
    float o0 = xo0 / (1.f + __expf(-z0));
    float o1 = xo1 / (1.f + __expf(-z1));

    // ---- 2x nearest upsample + add y (lane-contiguous float4 stores) ----
    *(float4*)(out + obase)      = make_float4(ya.x + o0, ya.y + o0, ya.z + o1, ya.w + o1);
    *(float4*)(out + obase + W2) = make_float4(yb.x + o0, yb.y + o0, yb.z + o1, yb.w + o1);
}

extern "C" void kernel_launch(void* const* d_in, const int* in_sizes, int n_in,
                              void* d_out, int out_size, void* d_ws, size_t ws_size,
                              hipStream_t stream) {
    const float* x  = (const float*)d_in[0];
    const float* y  = (const float*)d_in[1];
    const float* w1 = (const float*)d_in[2];
    const float* b1 = (const float*)d_in[3];
    const float* w2 = (const float*)d_in[4];
    const float* b2 = (const float*)d_in[5];
    float* out = (float*)d_out;

    constexpr int B = 8, C = 3, H = 512, W = 512;
    int total_threads = B * C * H * (W / 2);   // 3,145,728
    int block = 256;
    int grid  = total_threads / block;         // 12,288
    fused_kernel<<<grid, block, 0, stream>>>(x, y, w1, b1, w2, b2, out);
}

// Round 3
// 205.300 us; speedup vs baseline: 1.0091x; 1.0091x over previous
//
#include <hip/hip_runtime.h>

// Fused: per-channel affine+relu -> dilated(2) 3x3 box-sum (zero pad) ->
// sigmoid gate -> multiply -> 2x nearest upsample -> add y.
//
// Mapping: 1 thread = 2 adjacent input pixels (w0, w0+1) -> 4x2 output block.
// Lanes stride 16 B on y/out so every float4 load/store instruction is fully
// contiguous across the wave (R4 post-mortem).
// x taps: 3 float2 loads per row, UNCONDITIONAL with clamped addresses,
// masked arithmetically post-relu (R3). Plain cached stores (nt -> 2.5x WA).
//
// R5: XCD-chunked block swizzle (kept: -24 MB HBM fetch). 12288 % 8 == 0.
//
// R6 (failed instrument): asm "memory" clobber did NOT force load
// destinations live -- it orders memory ops only; the compiler interleaved
// consumption between loads and kept reusing 16 VGPRs, serializing ~11
// memory latencies per wave (~15K cy lifetime; why no pipe exceeds 40%).
//
// R7: pin by VALUE. A single asm taking every loaded element as "v" input
// forces all 26 destination registers simultaneously live at one program
// point -> loads issue back-to-back, ONE s_waitcnt vmcnt(0), then compute.
// sched_barrier(0) keeps the scheduler from hoisting ALU into the cluster.

#define DIA 2

__global__ __launch_bounds__(256) void fused_kernel(
    const float* __restrict__ x, const float* __restrict__ y,
    const float* __restrict__ w1v, const float* __restrict__ b1v,
    const float* __restrict__ w2v, const float* __restrict__ b2v,
    float* __restrict__ out)
{
    constexpr int C = 3, H = 512, W = 512, W2 = 1024;
    constexpr int NBLK = 12288, CHUNK = NBLK / 8;

    // XCD-aware swizzle: consecutive hardware blockIdx round-robins across
    // 8 XCDs; remap so each XCD owns a contiguous logical chunk.
    int g = blockIdx.x;
    int l = (g & 7) * CHUNK + (g >> 3);

    int idx = l * 256 + threadIdx.x;
    int wp = idx & (W / 2 - 1);                              // 0..255, lane-contiguous
    int h  = __builtin_amdgcn_readfirstlane((idx >> 8) & (H - 1));
    int bc = __builtin_amdgcn_readfirstlane(idx >> 17);      // 0..23 (b*C + c)
    int c  = bc % C;
    int w0 = wp * 2;                                         // even, 0..510

    const float s_w1 = w1v[c], s_b1 = b1v[c];
    const float s_w2 = w2v[c], s_b2 = b2v[c];

    const float* __restrict__ xrow = x + ((size_t)bc * H + (size_t)h) * W;

    const bool ok0 = (h >= DIA), ok2 = (h < H - DIA);
    const bool lok = (w0 > 0), rok = (w0 + 2 < W);
    const float m0 = ok0 ? 1.f : 0.f;
    const float m2 = ok2 ? 1.f : 0.f;
    const float mL = lok ? 1.f : 0.f;
    const float mR = rok ? 1.f : 0.f;

    // Clamped, always-in-bounds addresses (8B-aligned: offsets all even).
    const float* r1 = xrow;
    const float* r0 = ok0 ? (xrow - DIA * W) : xrow;
    const float* r2 = ok2 ? (xrow + DIA * W) : xrow;
    const int wl = lok ? (w0 - 2) : w0;
    const int wr = rok ? (w0 + 2) : w0;

    // ---- issue ALL global loads up front, unconditionally ----
    float2 L0 = *(const float2*)(r0 + wl);
    float2 M0 = *(const float2*)(r0 + w0);
    float2 R0 = *(const float2*)(r0 + wr);
    float2 L1 = *(const float2*)(r1 + wl);
    float2 M1 = *(const float2*)(r1 + w0);
    float2 R1 = *(const float2*)(r1 + wr);
    float2 L2 = *(const float2*)(r2 + wl);
    float2 M2 = *(const float2*)(r2 + w0);
    float2 R2 = *(const float2*)(r2 + wr);

    size_t obase = (((size_t)bc * (2 * H) + (size_t)(2 * h)) * W2) + (size_t)(2 * w0);
    float4 ya = *(const float4*)(y + obase);
    float4 yb = *(const float4*)(y + obase + W2);

    // R7: nothing may cross this point (no ALU hoisted into the load cluster).
    __builtin_amdgcn_sched_barrier(0);
    // R7: force EVERY loaded element live-in-register HERE. This is the
    // liveness pin the R6 "memory" clobber failed to provide: 26 VGPRs of
    // load destinations must coexist -> back-to-back issue, single vmcnt wait.
    asm volatile("" ::
        "v"(L0.x), "v"(L0.y), "v"(M0.x), "v"(M0.y), "v"(R0.x), "v"(R0.y),
        "v"(L1.x), "v"(L1.y), "v"(M1.x), "v"(M1.y), "v"(R1.x), "v"(R1.y),
        "v"(L2.x), "v"(L2.y), "v"(M2.x), "v"(M2.y), "v"(R2.x), "v"(R2.y),
        "v"(ya.x), "v"(ya.y), "v"(ya.z), "v"(ya.w),
        "v"(yb.x), "v"(yb.y), "v"(yb.z), "v"(yb.w));

    // ---- compute ----
    auto act = [&](float v) { return fmaxf(fmaf(v, s_w1, s_b1), 0.f); };

    // center (= x_r): always valid
    float xo0 = act(M1.x);
    float xo1 = act(M1.y);

    float sum0 = mL * act(L1.x) + xo0 + mR * act(R1.x);
    float sum1 = mL * act(L1.y) + xo1 + mR * act(R1.y);
    sum0 += m0 * (mL * act(L0.x) + act(M0.x) + mR * act(R0.x));
    sum1 += m0 * (mL * act(L0.y) + act(M0.y) + mR * act(R0.y));
    sum0 += m2 * (mL * act(L2.x) + act(M2.x) + mR * act(R2.x));
    sum1 += m2 * (mL * act(L2.y) + act(M2.y) + mR * act(R2.y));

    float z0 = fmaf(sum0, s_w2, s_b2);
    float z1 = fmaf(sum1, s_w2, s_b2);
    float o0 = xo0 / (1.f + __expf(-z0));
    float o1 = xo1 / (1.f + __expf(-z1));

    // ---- 2x nearest upsample + add y (lane-contiguous float4 stores) ----
    *(float4*)(out + obase)      = make_float4(ya.x + o0, ya.y + o0, ya.z + o1, ya.w + o1);
    *(float4*)(out + obase + W2) = make_float4(yb.x + o0, yb.y + o0, yb.z + o1, yb.w + o1);
}

extern "C" void kernel_launch(void* const* d_in, const int* in_sizes, int n_in,
                              void* d_out, int out_size, void* d_ws, size_t ws_size,
                              hipStream_t stream) {
    const float* x  = (const float*)d_in[0];
    const float* y  = (const float*)d_in[1];
    const float* w1 = (const float*)d_in[2];
    const float* b1 = (const float*)d_in[3];
    const float* w2 = (const float*)d_in[4];
    const float* b2 = (const float*)d_in[5];
    float* out = (float*)d_out;

    constexpr int B = 8, C = 3, H = 512, W = 512;
    int total_threads = B * C * H * (W / 2);   // 3,145,728
    int block = 256;
    int grid  = total_threads / block;         // 12,288
    fused_kernel<<<grid, block, 0, stream>>>(x, y, w1, b1, w2, b2, out);
}